// Round 7
// baseline (10496.992 us; speedup 1.0000x reference)
//
#include <hip/hip_runtime.h>
#include <math.h>

// B=8, N=4096, D=1024, E=512, C=4096.  M = 32768.
// Split-fp16 MFMA emulation of fp32 GEMM (a = h + l/2048, 3 MFMAs) for proj;
// hi-only fp16 pass for sim + deterministic margin rescue:
//   worst-case |sim_h - sim| <= 2^-10*||p||*||c|| + eps  < 0.03 = MARGIN
//   rows with top1-top2 < MARGIN recomputed with the exact 3-MFMA path.
// R7: k_simtop = C-sweep restructure. Block owns 64 m-rows, sweeps all 4096 c
//     (16 c-steps x 256c, K in 32-chunks). Running top-2 kept in registers,
//     folded at c-step boundaries (~3 VALU/val); the butterfly/merge epilogue
//     runs ONCE per block (was once per c-tile = 32x). A-tile frags shared by
//     all 4 waves. Writes out[] + contested list directly (k_flag removed).
//
// ws (MB): cn_h 0-4, cn_l 4-8, rpT_h 8-9, rpT_l 9-10, proj_h 10-42,
//          proj_l 42-74, rpv 86-90, rpi 90-94, list 94-94.125, cnt @94.125

typedef _Float16 half8 __attribute__((ext_vector_type(8)));
typedef _Float16 half4 __attribute__((ext_vector_type(4)));
typedef float f32x4 __attribute__((ext_vector_type(4)));

#define INV2048 (4.8828125e-4f)
#define MARGIN 0.03f

struct Split { _Float16 h, l; };

__device__ __forceinline__ Split split_f32(float v) {
    Split s;
    s.h = (_Float16)v;
    s.l = (_Float16)((v - (float)s.h) * 2048.0f);
    return s;
}

__device__ __forceinline__ void gl_lds16(const void* g, void* l) {
    __builtin_amdgcn_global_load_lds(
        (const __attribute__((address_space(1))) unsigned int*)g,
        (__attribute__((address_space(3))) unsigned int*)l, 16, 0, 0);
}

// rp [1024,512] fp32 -> rpT_hi/lo [512,1024] f16; also zero-inits cnt
__global__ __launch_bounds__(256) void k_prep_rpt(const float* __restrict__ rp,
                                                  _Float16* __restrict__ th,
                                                  _Float16* __restrict__ tl,
                                                  int* __restrict__ cnt) {
    if (blockIdx.x == 0 && blockIdx.y == 0 && threadIdx.x == 0) *cnt = 0;
    __shared__ float tile[64][65];
    const int k0 = blockIdx.x * 64, n0 = blockIdx.y * 64;
    const int t = threadIdx.x;
    const int rr = t >> 6, cc = t & 63;
    #pragma unroll
    for (int i = 0; i < 16; ++i) {
        int r = i * 4 + rr;
        tile[r][cc] = rp[(size_t)(k0 + r) * 512 + n0 + cc];
    }
    __syncthreads();
    #pragma unroll
    for (int i = 0; i < 16; ++i) {
        int n = i * 4 + rr;
        Split s = split_f32(tile[cc][n]);
        size_t o = (size_t)(n0 + n) * 1024 + k0 + cc;
        th[o] = s.h;
        tl[o] = s.l;
    }
}

// codebook [4096,512] fp32 -> cn_hi/lo [4096,512] f16 (normalize + split)
__global__ __launch_bounds__(256) void k_norm_cb(const float* __restrict__ cb,
                                                 _Float16* __restrict__ ch,
                                                 _Float16* __restrict__ cl) {
    const int c = blockIdx.x;
    const int t = threadIdx.x;
    const float* row = cb + (size_t)c * 512;
    float v0 = row[t];
    float v1 = row[t + 256];
    float ss = v0 * v0 + v1 * v1;
    #pragma unroll
    for (int o = 32; o > 0; o >>= 1) ss += __shfl_down(ss, o, 64);
    __shared__ float wsum[4];
    if ((t & 63) == 0) wsum[t >> 6] = ss;
    __syncthreads();
    float s = 1.0f / fmaxf(sqrtf(wsum[0] + wsum[1] + wsum[2] + wsum[3]), 1e-12f);
    Split s0 = split_f32(v0 * s);
    ch[(size_t)c * 512 + t] = s0.h;
    cl[(size_t)c * 512 + t] = s0.l;
    Split s1 = split_f32(v1 * s);
    ch[(size_t)c * 512 + t + 256] = s1.h;
    cl[(size_t)c * 512 + t + 256] = s1.l;
}

// proj = x @ rp : M=32768, N=512, K=1024. split-fp16 3-MFMA (accurate).
__global__ __launch_bounds__(256, 2) void k_gemm1(const float* __restrict__ X,
                                                  const _Float16* __restrict__ Bh,
                                                  const _Float16* __restrict__ Bl,
                                                  _Float16* __restrict__ Ph,
                                                  _Float16* __restrict__ Pl) {
    __shared__ _Float16 sAh[128 * 32], sAl[128 * 32], sBh[128 * 32], sBl[128 * 32];
    const int t = threadIdx.x;
    const int nb = blockIdx.x;   // 0..3
    const int mb = blockIdx.y;   // 0..255
    const int lane = t & 63, w = t >> 6;
    const int quad = lane >> 4, l15 = lane & 15;
    const int wm = w >> 1, wn = w & 1;

    f32x4 acc[4][4], acc2[4][4];
    const f32x4 z = {0.f, 0.f, 0.f, 0.f};
    #pragma unroll
    for (int i = 0; i < 4; ++i)
        #pragma unroll
        for (int j = 0; j < 4; ++j) { acc[i][j] = z; acc2[i][j] = z; }

    const int srow = w * 32 + (lane >> 2);
    const int kcol = (lane & 3) * 8;
    const _Float16* gBh = Bh + (size_t)(nb * 128 + srow) * 1024 + kcol;
    const _Float16* gBl = Bl + (size_t)(nb * 128 + srow) * 1024 + kcol;
    const float* Xb = X + (size_t)(mb * 128) * 1024;

    for (int ks = 0; ks < 32; ++ks) {
        const int ko = ks * 32;
        __syncthreads();
        gl_lds16(gBh + ko, &sBh[w * 1024]);
        gl_lds16(gBh + ko + (size_t)16 * 1024, &sBh[w * 1024 + 512]);
        gl_lds16(gBl + ko, &sBl[w * 1024]);
        gl_lds16(gBl + ko + (size_t)16 * 1024, &sBl[w * 1024 + 512]);
        #pragma unroll
        for (int i = 0; i < 4; ++i) {
            int c = i * 256 + t;
            int row = c >> 3, kq = (c & 7) * 4;
            float4 v = *(const float4*)(Xb + (size_t)row * 1024 + ko + kq);
            Split sx = split_f32(v.x), sy = split_f32(v.y);
            Split sz = split_f32(v.z), sw = split_f32(v.w);
            half4 hv, lv;
            hv.x = sx.h; hv.y = sy.h; hv.z = sz.h; hv.w = sw.h;
            lv.x = sx.l; lv.y = sy.l; lv.z = sz.l; lv.w = sw.l;
            *(half4*)&sAh[row * 32 + kq] = hv;
            *(half4*)&sAl[row * 32 + kq] = lv;
        }
        __syncthreads();
        half8 ah[4], al[4], bh[4], bl[4];
        #pragma unroll
        for (int i = 0; i < 4; ++i) {
            ah[i] = *(const half8*)&sAh[(wm * 64 + i * 16 + l15) * 32 + quad * 8];
            al[i] = *(const half8*)&sAl[(wm * 64 + i * 16 + l15) * 32 + quad * 8];
            bh[i] = *(const half8*)&sBh[(wn * 64 + i * 16 + l15) * 32 + quad * 8];
            bl[i] = *(const half8*)&sBl[(wn * 64 + i * 16 + l15) * 32 + quad * 8];
        }
        #pragma unroll
        for (int mi = 0; mi < 4; ++mi)
            #pragma unroll
            for (int ni = 0; ni < 4; ++ni) {
                acc[mi][ni]  = __builtin_amdgcn_mfma_f32_16x16x32_f16(ah[mi], bh[ni], acc[mi][ni], 0, 0, 0);
                acc2[mi][ni] = __builtin_amdgcn_mfma_f32_16x16x32_f16(ah[mi], bl[ni], acc2[mi][ni], 0, 0, 0);
                acc2[mi][ni] = __builtin_amdgcn_mfma_f32_16x16x32_f16(al[mi], bh[ni], acc2[mi][ni], 0, 0, 0);
            }
    }
    #pragma unroll
    for (int mi = 0; mi < 4; ++mi)
        #pragma unroll
        for (int r = 0; r < 4; ++r) {
            int row = mb * 128 + wm * 64 + mi * 16 + quad * 4 + r;
            #pragma unroll
            for (int ni = 0; ni < 4; ++ni) {
                int col = nb * 128 + wn * 64 + ni * 16 + l15;
                float v = acc[mi][ni][r] + acc2[mi][ni][r] * INV2048;
                Split s = split_f32(v);
                Ph[(size_t)row * 512 + col] = s.h;
                Pl[(size_t)row * 512 + col] = s.l;
            }
        }
}

// PASS 1: hi-only sim, C-sweep. Block = 64 m-rows x all 4096 c.
// 4 waves (wn=w), wave tile 64m x 64c per 256c c-step. Ping-pong LDS,
// prefetch after barrier, XOR k-seg swizzle (r6-verified pattern).
__global__ __launch_bounds__(256, 2) void k_simtop(const _Float16* __restrict__ Ah,
                                                   const _Float16* __restrict__ Bh,
                                                   int* __restrict__ out,
                                                   int* __restrict__ list,
                                                   int* __restrict__ cnt) {
    __shared__ _Float16 sA[2][64 * 32];    // 4 KB per buf
    __shared__ _Float16 sB[2][256 * 32];   // 16 KB per buf
    __shared__ float fv1[64][4], fv2[64][4];
    __shared__ int   fi1[64][4];
    const int t = threadIdx.x;
    const int mb = blockIdx.x;             // 0..511, rows mb*64..+64
    const int lane = t & 63, w = t >> 6;   // w = wn in 0..3
    const int quad = lane >> 4, l15 = lane & 15;
    const int sw8 = (quad ^ ((l15 >> 1) & 3)) * 8;

    // staging pattern (r6-verified): lane ell -> chunk row ell>>2,
    // global k-seg (ell&3)^((ell>>3)&3); LDS dest = base + ell*16B.
    const int srow = lane >> 2;
    const int kseg = (lane & 3) ^ ((lane >> 3) & 3);
    const _Float16* gA  = Ah + (size_t)(mb * 64 + w * 16 + srow) * 512 + kseg * 8;
    const _Float16* gB0 = Bh + (size_t)(w * 64 + srow) * 512 + kseg * 8;

    f32x4 acc[4][4];
    const f32x4 z = {0.f, 0.f, 0.f, 0.f};
    #pragma unroll
    for (int i = 0; i < 4; ++i)
        #pragma unroll
        for (int j = 0; j < 4; ++j) acc[i][j] = z;

    float rv1[16], rv2[16];
    int   ri1[16];
    #pragma unroll
    for (int s = 0; s < 16; ++s) { rv1[s] = -INFINITY; rv2[s] = -INFINITY; ri1[s] = 0x7fffffff; }

    // prologue: stage it=0 (cs=0, ks=0) into buf 0
    gl_lds16(gA, &sA[0][w * 512]);
    #pragma unroll
    for (int j = 0; j < 4; ++j)
        gl_lds16(gB0 + (size_t)(j * 16) * 512, &sB[0][w * 2048 + j * 512]);

    for (int it = 0; it < 256; ++it) {   // it = cs*16 + ks
        const int p = it & 1;
        __syncthreads();   // drains prefetch issued last iter; guards buf reuse
        if (it + 1 < 256) {
            const int nit = it + 1;
            const int nks = nit & 15, ncs = nit >> 4;
            const int ko = nks * 32;
            gl_lds16(gA + ko, &sA[p ^ 1][w * 512]);
            const _Float16* gB = gB0 + (size_t)(ncs * 256) * 512 + ko;
            #pragma unroll
            for (int j = 0; j < 4; ++j)
                gl_lds16(gB + (size_t)(j * 16) * 512, &sB[p ^ 1][w * 2048 + j * 512]);
        }
        half8 a[4], b[4];
        #pragma unroll
        for (int i = 0; i < 4; ++i) {
            a[i] = *(const half8*)&sA[p][(i * 16 + l15) * 32 + sw8];
            b[i] = *(const half8*)&sB[p][(w * 64 + i * 16 + l15) * 32 + sw8];
        }
        #pragma unroll
        for (int mi = 0; mi < 4; ++mi)
            #pragma unroll
            for (int ni = 0; ni < 4; ++ni)
                acc[mi][ni] = __builtin_amdgcn_mfma_f32_16x16x32_f16(a[mi], b[ni], acc[mi][ni], 0, 0, 0);

        if ((it & 15) == 15) {   // end of c-step: fold into running top-2, reset acc
            const int cs = it >> 4;
            #pragma unroll
            for (int mi = 0; mi < 4; ++mi)
                #pragma unroll
                for (int r = 0; r < 4; ++r) {
                    const int s = mi * 4 + r;
                    #pragma unroll
                    for (int ni = 0; ni < 4; ++ni) {
                        float v = acc[mi][ni][r];
                        int col = cs * 256 + w * 64 + ni * 16 + l15;
                        if (v > rv1[s]) { rv2[s] = rv1[s]; rv1[s] = v; ri1[s] = col; }
                        else if (v > rv2[s]) rv2[s] = v;
                        acc[mi][ni][r] = 0.f;
                    }
                }
        }
    }

    // once-per-block merge: 16-lane butterfly within quad-group
    #pragma unroll
    for (int s = 0; s < 16; ++s) {
        float v1 = rv1[s], v2 = rv2[s];
        int i1 = ri1[s];
        #pragma unroll
        for (int o = 1; o < 16; o <<= 1) {
            float ov1 = __shfl_xor(v1, o, 64);
            int oi1 = __shfl_xor(i1, o, 64);
            float ov2 = __shfl_xor(v2, o, 64);
            if (ov1 > v1 || (ov1 == v1 && oi1 < i1)) { v2 = fmaxf(v1, ov2); v1 = ov1; i1 = oi1; }
            else v2 = fmaxf(v2, ov1);
        }
        if (l15 == 0) {
            int row = (s >> 2) * 16 + quad * 4 + (s & 3);
            fv1[row][w] = v1; fi1[row][w] = i1; fv2[row][w] = v2;
        }
    }
    __syncthreads();
    if (t < 64) {
        float v1 = fv1[t][0], v2 = fv2[t][0];
        int i1 = fi1[t][0];
        #pragma unroll
        for (int j = 1; j < 4; ++j) {
            float ov1 = fv1[t][j], ov2 = fv2[t][j];
            int oi1 = fi1[t][j];
            if (ov1 > v1 || (ov1 == v1 && oi1 < i1)) { v2 = fmaxf(v1, ov2); v1 = ov1; i1 = oi1; }
            else v2 = fmaxf(v2, ov1);
        }
        int row = mb * 64 + t;
        out[row] = i1;
        if (v1 - v2 < MARGIN) {
            int p = atomicAdd(cnt, 1);
            list[p] = row;
        }
    }
}

// PASS 2: exact 3-MFMA sim on gathered contested rows
__global__ __launch_bounds__(256, 2) void k_sim_fix(const _Float16* __restrict__ Ah,
                                                    const _Float16* __restrict__ Al,
                                                    const _Float16* __restrict__ Bh,
                                                    const _Float16* __restrict__ Bl,
                                                    const int* __restrict__ list,
                                                    const int* __restrict__ cnt,
                                                    float* __restrict__ rpv,
                                                    int* __restrict__ rpi) {
    __shared__ _Float16 sAh[128 * 32], sAl[128 * 32], sBh[128 * 32], sBl[128 * 32];
    __shared__ int rowidx[128];
    __shared__ float pvs[128][2];
    __shared__ int   pis[128][2];
    const int count = *cnt;
    const int t = threadIdx.x;
    const int cbk = blockIdx.x;  // 0..31
    const int lane = t & 63, w = t >> 6;
    const int quad = lane >> 4, l15 = lane & 15;
    const int wm = w >> 1, wn = w & 1;

    const int srow = w * 32 + (lane >> 2);
    const int kcol = (lane & 3) * 8;
    const _Float16* gBh = Bh + (size_t)(cbk * 128 + srow) * 512 + kcol;
    const _Float16* gBl = Bl + (size_t)(cbk * 128 + srow) * 512 + kcol;

    for (int g = blockIdx.y; g * 128 < count; g += gridDim.y) {
        __syncthreads();
        if (t < 128) {
            int p = g * 128 + t;
            rowidx[t] = (p < count) ? list[p] : list[0];
        }
        __syncthreads();

        f32x4 acc[4][4], acc2[4][4];
        const f32x4 z = {0.f, 0.f, 0.f, 0.f};
        #pragma unroll
        for (int i = 0; i < 4; ++i)
            #pragma unroll
            for (int j = 0; j < 4; ++j) { acc[i][j] = z; acc2[i][j] = z; }

        for (int ks = 0; ks < 16; ++ks) {
            const int ko = ks * 32;
            __syncthreads();
            gl_lds16(gBh + ko, &sBh[w * 1024]);
            gl_lds16(gBh + ko + (size_t)16 * 512, &sBh[w * 1024 + 512]);
            gl_lds16(gBl + ko, &sBl[w * 1024]);
            gl_lds16(gBl + ko + (size_t)16 * 512, &sBl[w * 1024 + 512]);
            #pragma unroll
            for (int i = 0; i < 2; ++i) {
                int idx = i * 256 + t;          // 0..511
                int row = idx >> 2, seg = (idx & 3) * 8;
                size_t src = (size_t)rowidx[row] * 512 + ko + seg;
                *(half8*)&sAh[row * 32 + seg] = *(const half8*)(Ah + src);
                *(half8*)&sAl[row * 32 + seg] = *(const half8*)(Al + src);
            }
            __syncthreads();
            half8 ah[4], al[4], bh[4], bl[4];
            #pragma unroll
            for (int i = 0; i < 4; ++i) {
                ah[i] = *(const half8*)&sAh[(wm * 64 + i * 16 + l15) * 32 + quad * 8];
                al[i] = *(const half8*)&sAl[(wm * 64 + i * 16 + l15) * 32 + quad * 8];
                bh[i] = *(const half8*)&sBh[(wn * 64 + i * 16 + l15) * 32 + quad * 8];
                bl[i] = *(const half8*)&sBl[(wn * 64 + i * 16 + l15) * 32 + quad * 8];
            }
            #pragma unroll
            for (int mi = 0; mi < 4; ++mi)
                #pragma unroll
                for (int ni = 0; ni < 4; ++ni) {
                    acc[mi][ni]  = __builtin_amdgcn_mfma_f32_16x16x32_f16(ah[mi], bh[ni], acc[mi][ni], 0, 0, 0);
                    acc2[mi][ni] = __builtin_amdgcn_mfma_f32_16x16x32_f16(ah[mi], bl[ni], acc2[mi][ni], 0, 0, 0);
                    acc2[mi][ni] = __builtin_amdgcn_mfma_f32_16x16x32_f16(al[mi], bh[ni], acc2[mi][ni], 0, 0, 0);
                }
        }

        #pragma unroll
        for (int mi = 0; mi < 4; ++mi)
            #pragma unroll
            for (int r = 0; r < 4; ++r) {
                float bv = -INFINITY;
                int bi = 0x7fffffff;
                #pragma unroll
                for (int ni = 0; ni < 4; ++ni) {
                    float v = acc[mi][ni][r] + acc2[mi][ni][r] * INV2048;
                    int col = cbk * 128 + wn * 64 + ni * 16 + l15;
                    if (v > bv || (v == bv && col < bi)) { bv = v; bi = col; }
                }
                #pragma unroll
                for (int o = 1; o < 16; o <<= 1) {
                    float ov = __shfl_xor(bv, o, 64);
                    int oi = __shfl_xor(bi, o, 64);
                    if (ov > bv || (ov == bv && oi < bi)) { bv = ov; bi = oi; }
                }
                if (l15 == 0) {
                    int row = wm * 64 + mi * 16 + quad * 4 + r;
                    pvs[row][wn] = bv; pis[row][wn] = bi;
                }
            }
        __syncthreads();
        if (t < 128 && g * 128 + t < count) {
            float v0 = pvs[t][0], v1 = pvs[t][1];
            int i0 = pis[t][0], i1 = pis[t][1];
            bool sw = (v1 > v0) || (v1 == v0 && i1 < i0);
            size_t o = (size_t)(g * 128 + t) * 32 + cbk;
            rpv[o] = sw ? v1 : v0;
            rpi[o] = sw ? i1 : i0;
        }
    }
}

__global__ __launch_bounds__(256) void k_fix(const float* __restrict__ rpv,
                                             const int* __restrict__ rpi,
                                             const int* __restrict__ list,
                                             const int* __restrict__ cnt,
                                             int* __restrict__ out) {
    int p = blockIdx.x * 256 + threadIdx.x;
    if (p >= *cnt) return;
    size_t base = (size_t)p * 32;
    float bv = -INFINITY;
    int bi = 0x7fffffff;
    #pragma unroll
    for (int j = 0; j < 32; ++j) {
        float v = rpv[base + j];
        int ci = rpi[base + j];
        if (v > bv || (v == bv && ci < bi)) { bv = v; bi = ci; }
    }
    out[list[p]] = bi;
}

extern "C" void kernel_launch(void* const* d_in, const int* in_sizes, int n_in,
                              void* d_out, int out_size, void* d_ws, size_t ws_size,
                              hipStream_t stream) {
    const float* x  = (const float*)d_in[0];   // [8,4096,1024]
    const float* rp = (const float*)d_in[1];   // [1024,512]
    const float* cb = (const float*)d_in[2];   // [4096,512]
    int* out = (int*)d_out;                    // [32768] int32

    char* ws = (char*)d_ws;
    _Float16* cn_h   = (_Float16*)(ws);
    _Float16* cn_l   = (_Float16*)(ws + ((size_t)4 << 20));
    _Float16* rpT_h  = (_Float16*)(ws + ((size_t)8 << 20));
    _Float16* rpT_l  = (_Float16*)(ws + ((size_t)9 << 20));
    _Float16* proj_h = (_Float16*)(ws + ((size_t)10 << 20));
    _Float16* proj_l = (_Float16*)(ws + ((size_t)42 << 20));
    float*    rpv    = (float*)   (ws + ((size_t)86 << 20));
    int*      rpi    = (int*)     (ws + ((size_t)90 << 20));
    int*      list   = (int*)     (ws + ((size_t)94 << 20));
    int*      cnt    = (int*)     (ws + ((size_t)94 << 20) + (128 << 10));

    k_prep_rpt<<<dim3(16, 8), 256, 0, stream>>>(rp, rpT_h, rpT_l, cnt);
    k_norm_cb<<<4096, 256, 0, stream>>>(cb, cn_h, cn_l);
    k_gemm1<<<dim3(4, 256), 256, 0, stream>>>(x, rpT_h, rpT_l, proj_h, proj_l);
    k_simtop<<<512, 256, 0, stream>>>(proj_h, cn_h, out, list, cnt);
    k_sim_fix<<<dim3(32, 32), 256, 0, stream>>>(proj_h, proj_l, cn_h, cn_l, list, cnt, rpv, rpi);
    k_fix<<<128, 256, 0, stream>>>(rpv, rpi, list, cnt, out);
}

// Round 8
// 560.873 us; speedup vs baseline: 18.7154x; 18.7154x over previous
//
#include <hip/hip_runtime.h>
#include <math.h>

// B=8, N=4096, D=1024, E=512, C=4096.  M = 32768.
// Split-fp16 MFMA emulation of fp32 GEMM (a = h + l/2048, 3 MFMAs) for proj;
// hi-only fp16 pass for sim + deterministic margin rescue:
//   worst-case |sim_h - sim| <= 2^-10*||p||*||c|| + eps  < 0.03 = MARGIN
//   rows with top1-top2 < MARGIN recomputed with the exact 3-MFMA path.
// R8: k_sim_h = r4 grid/loop (2-barrier, BK=32) + r6 XOR swizzle (0 conflicts)
//     + LDS-table epilogue: packed u64 (float-key<<32 | ~col) lane-local top-2
//     -> 48KB table (union w/ staging) -> 128-thread serial merge. Replaces
//     768 ds_bpermute/block with ~96KB of conflict-free LDS traffic.
//
// ws (MB): cn_h 0-4, cn_l 4-8, rpT_h 8-9, rpT_l 9-10, proj_h 10-42,
//          proj_l 42-74, pv1 74-78, pi1 78-82, pv2 82-86, rpv 86-90,
//          rpi 90-94, list 94-94.125, cnt @94.125

typedef _Float16 half8 __attribute__((ext_vector_type(8)));
typedef _Float16 half4 __attribute__((ext_vector_type(4)));
typedef float f32x4 __attribute__((ext_vector_type(4)));
typedef unsigned long long u64;
typedef unsigned int u32;

#define INV2048 (4.8828125e-4f)
#define MARGIN 0.03f

struct Split { _Float16 h, l; };

__device__ __forceinline__ Split split_f32(float v) {
    Split s;
    s.h = (_Float16)v;
    s.l = (_Float16)((v - (float)s.h) * 2048.0f);
    return s;
}

__device__ __forceinline__ void gl_lds16(const void* g, void* l) {
    __builtin_amdgcn_global_load_lds(
        (const __attribute__((address_space(1))) unsigned int*)g,
        (__attribute__((address_space(3))) unsigned int*)l, 16, 0, 0);
}

// monotone float->u32 key (finite inputs): order-preserving, key>0
__device__ __forceinline__ u32 fkey(float v) {
    u32 b = __float_as_uint(v);
    return b ^ ((u32)((int)b >> 31) | 0x80000000u);
}
__device__ __forceinline__ float fkeyinv(u32 u) {
    u32 m2 = (u32)((int)u >> 31);            // FFFF.. if top bit set
    return __uint_as_float(u ^ ((~m2) | 0x80000000u));
}

// fused: blocks 0..127 transpose+split rp; blocks 128..4223 normalize+split cb
__global__ __launch_bounds__(256) void k_prep(const float* __restrict__ rp,
                                              _Float16* __restrict__ th,
                                              _Float16* __restrict__ tl,
                                              const float* __restrict__ cb,
                                              _Float16* __restrict__ ch,
                                              _Float16* __restrict__ cl,
                                              int* __restrict__ cnt) {
    const int t = threadIdx.x;
    if (blockIdx.x == 0 && t == 0) *cnt = 0;
    if (blockIdx.x < 128) {
        __shared__ float tile[64][65];
        const int k0 = (blockIdx.x & 15) * 64, n0 = (blockIdx.x >> 4) * 64;
        const int rr = t >> 6, cc = t & 63;
        #pragma unroll
        for (int i = 0; i < 16; ++i) {
            int r = i * 4 + rr;
            tile[r][cc] = rp[(size_t)(k0 + r) * 512 + n0 + cc];
        }
        __syncthreads();
        #pragma unroll
        for (int i = 0; i < 16; ++i) {
            int n = i * 4 + rr;
            Split s = split_f32(tile[cc][n]);
            size_t o = (size_t)(n0 + n) * 1024 + k0 + cc;
            th[o] = s.h;
            tl[o] = s.l;
        }
    } else {
        const int c = blockIdx.x - 128;
        const float* row = cb + (size_t)c * 512;
        float v0 = row[t];
        float v1 = row[t + 256];
        float ss = v0 * v0 + v1 * v1;
        #pragma unroll
        for (int o = 32; o > 0; o >>= 1) ss += __shfl_down(ss, o, 64);
        __shared__ float wsum[4];
        if ((t & 63) == 0) wsum[t >> 6] = ss;
        __syncthreads();
        float s = 1.0f / fmaxf(sqrtf(wsum[0] + wsum[1] + wsum[2] + wsum[3]), 1e-12f);
        Split s0 = split_f32(v0 * s);
        ch[(size_t)c * 512 + t] = s0.h;
        cl[(size_t)c * 512 + t] = s0.l;
        Split s1 = split_f32(v1 * s);
        ch[(size_t)c * 512 + t + 256] = s1.h;
        cl[(size_t)c * 512 + t + 256] = s1.l;
    }
}

// proj = x @ rp : M=32768, N=512, K=1024. split-fp16 3-MFMA (accurate).
__global__ __launch_bounds__(256, 2) void k_gemm1(const float* __restrict__ X,
                                                  const _Float16* __restrict__ Bh,
                                                  const _Float16* __restrict__ Bl,
                                                  _Float16* __restrict__ Ph,
                                                  _Float16* __restrict__ Pl) {
    __shared__ _Float16 sAh[128 * 32], sAl[128 * 32], sBh[128 * 32], sBl[128 * 32];
    const int t = threadIdx.x;
    const int nb = blockIdx.x;   // 0..3
    const int mb = blockIdx.y;   // 0..255
    const int lane = t & 63, w = t >> 6;
    const int quad = lane >> 4, l15 = lane & 15;
    const int wm = w >> 1, wn = w & 1;

    f32x4 acc[4][4], acc2[4][4];
    const f32x4 z = {0.f, 0.f, 0.f, 0.f};
    #pragma unroll
    for (int i = 0; i < 4; ++i)
        #pragma unroll
        for (int j = 0; j < 4; ++j) { acc[i][j] = z; acc2[i][j] = z; }

    const int srow = w * 32 + (lane >> 2);
    const int kcol = (lane & 3) * 8;
    const _Float16* gBh = Bh + (size_t)(nb * 128 + srow) * 1024 + kcol;
    const _Float16* gBl = Bl + (size_t)(nb * 128 + srow) * 1024 + kcol;
    const float* Xb = X + (size_t)(mb * 128) * 1024;

    for (int ks = 0; ks < 32; ++ks) {
        const int ko = ks * 32;
        __syncthreads();
        gl_lds16(gBh + ko, &sBh[w * 1024]);
        gl_lds16(gBh + ko + (size_t)16 * 1024, &sBh[w * 1024 + 512]);
        gl_lds16(gBl + ko, &sBl[w * 1024]);
        gl_lds16(gBl + ko + (size_t)16 * 1024, &sBl[w * 1024 + 512]);
        #pragma unroll
        for (int i = 0; i < 4; ++i) {
            int c = i * 256 + t;
            int row = c >> 3, kq = (c & 7) * 4;
            float4 v = *(const float4*)(Xb + (size_t)row * 1024 + ko + kq);
            Split sx = split_f32(v.x), sy = split_f32(v.y);
            Split sz = split_f32(v.z), sw = split_f32(v.w);
            half4 hv, lv;
            hv.x = sx.h; hv.y = sy.h; hv.z = sz.h; hv.w = sw.h;
            lv.x = sx.l; lv.y = sy.l; lv.z = sz.l; lv.w = sw.l;
            *(half4*)&sAh[row * 32 + kq] = hv;
            *(half4*)&sAl[row * 32 + kq] = lv;
        }
        __syncthreads();
        half8 ah[4], al[4], bh[4], bl[4];
        #pragma unroll
        for (int i = 0; i < 4; ++i) {
            ah[i] = *(const half8*)&sAh[(wm * 64 + i * 16 + l15) * 32 + quad * 8];
            al[i] = *(const half8*)&sAl[(wm * 64 + i * 16 + l15) * 32 + quad * 8];
            bh[i] = *(const half8*)&sBh[(wn * 64 + i * 16 + l15) * 32 + quad * 8];
            bl[i] = *(const half8*)&sBl[(wn * 64 + i * 16 + l15) * 32 + quad * 8];
        }
        #pragma unroll
        for (int mi = 0; mi < 4; ++mi)
            #pragma unroll
            for (int ni = 0; ni < 4; ++ni) {
                acc[mi][ni]  = __builtin_amdgcn_mfma_f32_16x16x32_f16(ah[mi], bh[ni], acc[mi][ni], 0, 0, 0);
                acc2[mi][ni] = __builtin_amdgcn_mfma_f32_16x16x32_f16(ah[mi], bl[ni], acc2[mi][ni], 0, 0, 0);
                acc2[mi][ni] = __builtin_amdgcn_mfma_f32_16x16x32_f16(al[mi], bh[ni], acc2[mi][ni], 0, 0, 0);
            }
    }
    #pragma unroll
    for (int mi = 0; mi < 4; ++mi)
        #pragma unroll
        for (int r = 0; r < 4; ++r) {
            int row = mb * 128 + wm * 64 + mi * 16 + quad * 4 + r;
            #pragma unroll
            for (int ni = 0; ni < 4; ++ni) {
                int col = nb * 128 + wn * 64 + ni * 16 + l15;
                float v = acc[mi][ni][r] + acc2[mi][ni][r] * INV2048;
                Split s = split_f32(v);
                Ph[(size_t)row * 512 + col] = s.h;
                Pl[(size_t)row * 512 + col] = s.l;
            }
        }
}

// PASS 1: hi-only sim. r4 2-barrier loop + XOR swizzle; LDS-table epilogue.
__global__ __launch_bounds__(256, 3) void k_sim_h(const _Float16* __restrict__ Ah,
                                                  const _Float16* __restrict__ Bh,
                                                  float* __restrict__ pv1,
                                                  int* __restrict__ pi1,
                                                  float* __restrict__ pv2) {
    __shared__ __align__(16) long long smem64[6144];   // 48 KB
    _Float16* sA = (_Float16*)smem64;                  // [128][32] halfs, 8 KB
    _Float16* sB = sA + 4096;                          // 8 KB
    u64* ept = (u64*)smem64;                           // [128][32] u64, 32 KB
    u32* epv = (u32*)((char*)smem64 + 32768);          // [128][32] u32, 16 KB
    const int t = threadIdx.x;
    const int cbk = blockIdx.x;  // 0..31
    const int mb = blockIdx.y;   // 0..255
    const int lane = t & 63, w = t >> 6;
    const int quad = lane >> 4, l15 = lane & 15;
    const int wm = w >> 1, wn = w & 1;

    f32x4 acc[4][4];
    const f32x4 z = {0.f, 0.f, 0.f, 0.f};
    #pragma unroll
    for (int i = 0; i < 4; ++i)
        #pragma unroll
        for (int j = 0; j < 4; ++j) acc[i][j] = z;

    // swizzled staging (r6-verified): lane ell -> row ell>>2, global k-seg
    // (ell&3)^((ell>>3)&3); realizes LDS(row,slot)=G(row, slot^((row>>1)&3)).
    const int srow = lane >> 2;
    const int kseg = (lane & 3) ^ ((lane >> 3) & 3);
    const _Float16* gA = Ah + (size_t)(mb * 128 + w * 32 + srow) * 512 + kseg * 8;
    const _Float16* gB = Bh + (size_t)(cbk * 128 + w * 32 + srow) * 512 + kseg * 8;
    const int sw8 = (quad ^ ((l15 >> 1) & 3)) * 8;

    for (int ks = 0; ks < 16; ++ks) {
        const int ko = ks * 32;
        __syncthreads();
        gl_lds16(gA + ko, &sA[w * 1024]);
        gl_lds16(gA + ko + (size_t)16 * 512, &sA[w * 1024 + 512]);
        gl_lds16(gB + ko, &sB[w * 1024]);
        gl_lds16(gB + ko + (size_t)16 * 512, &sB[w * 1024 + 512]);
        __syncthreads();
        half8 a[4], b[4];
        #pragma unroll
        for (int i = 0; i < 4; ++i) {
            a[i] = *(const half8*)&sA[(wm * 64 + i * 16 + l15) * 32 + sw8];
            b[i] = *(const half8*)&sB[(wn * 64 + i * 16 + l15) * 32 + sw8];
        }
        #pragma unroll
        for (int mi = 0; mi < 4; ++mi)
            #pragma unroll
            for (int ni = 0; ni < 4; ++ni)
                acc[mi][ni] = __builtin_amdgcn_mfma_f32_16x16x32_f16(a[mi], b[ni], acc[mi][ni], 0, 0, 0);
    }

    __syncthreads();   // all waves done reading sA/sB; reuse as epilogue table
    // lane-local top-2 over ni (packed u64: fkey(v)<<32 | ~col -> numpy ties)
    #pragma unroll
    for (int mi = 0; mi < 4; ++mi)
        #pragma unroll
        for (int r = 0; r < 4; ++r) {
            int row = wm * 64 + mi * 16 + quad * 4 + r;
            u64 p1 = 0, p2 = 0;
            #pragma unroll
            for (int ni = 0; ni < 4; ++ni) {
                float v = acc[mi][ni][r];
                u32 col = cbk * 128 + wn * 64 + ni * 16 + l15;
                u64 p = ((u64)fkey(v) << 32) | (u32)(~col);
                if (p > p1) { p2 = p1; p1 = p; }
                else if (p > p2) p2 = p;
            }
            int e = row * 32 + wn * 16 + l15;
            ept[e] = p1;
            epv[e] = (u32)(p2 >> 32);
        }
    __syncthreads();
    if (t < 128) {
        u64 b1 = 0, b2 = 0;
        u32 vk2 = 0;
        #pragma unroll
        for (int jj = 0; jj < 32; ++jj) {
            int j = (jj + t) & 31;   // staggered: avoids same-bank lockstep
            u64 p = ept[t * 32 + j];
            if (p > b1) { b2 = b1; b1 = p; }
            else if (p > b2) b2 = p;
            u32 vk = epv[t * 32 + j];
            vk2 = vk > vk2 ? vk : vk2;
        }
        u32 k2 = (u32)(b2 >> 32);
        if (vk2 > k2) k2 = vk2;
        float v1 = fkeyinv((u32)(b1 >> 32));
        int col = (int)(~(u32)b1);
        size_t o = (size_t)(mb * 128 + t) * 32 + cbk;
        pv1[o] = v1;
        pi1[o] = col;
        pv2[o] = fkeyinv(k2);
    }
}

// reduce 32 c-tile partials; commit confident rows, queue contested ones
__global__ __launch_bounds__(256) void k_flag(const float* __restrict__ pv1,
                                              const int* __restrict__ pi1,
                                              const float* __restrict__ pv2,
                                              int* __restrict__ out,
                                              int* __restrict__ list,
                                              int* __restrict__ cnt) {
    int r = blockIdx.x * 256 + threadIdx.x;
    if (r >= 32768) return;
    size_t base = (size_t)r * 32;
    float v1 = pv1[base], v2 = pv2[base];
    int i1 = pi1[base];
    #pragma unroll
    for (int j = 1; j < 32; ++j) {
        float ov1 = pv1[base + j], ov2 = pv2[base + j];
        int oi1 = pi1[base + j];
        if (ov1 > v1 || (ov1 == v1 && oi1 < i1)) { v2 = fmaxf(v1, ov2); v1 = ov1; i1 = oi1; }
        else v2 = fmaxf(v2, ov1);
    }
    out[r] = i1;
    if (v1 - v2 < MARGIN) {
        int p = atomicAdd(cnt, 1);
        list[p] = r;
    }
}

// PASS 2: exact 3-MFMA sim on gathered contested rows
__global__ __launch_bounds__(256, 2) void k_sim_fix(const _Float16* __restrict__ Ah,
                                                    const _Float16* __restrict__ Al,
                                                    const _Float16* __restrict__ Bh,
                                                    const _Float16* __restrict__ Bl,
                                                    const int* __restrict__ list,
                                                    const int* __restrict__ cnt,
                                                    float* __restrict__ rpv,
                                                    int* __restrict__ rpi) {
    __shared__ _Float16 sAh[128 * 32], sAl[128 * 32], sBh[128 * 32], sBl[128 * 32];
    __shared__ int rowidx[128];
    __shared__ float pvs[128][2];
    __shared__ int   pis[128][2];
    const int count = *cnt;
    const int t = threadIdx.x;
    const int cbk = blockIdx.x;  // 0..31
    const int lane = t & 63, w = t >> 6;
    const int quad = lane >> 4, l15 = lane & 15;
    const int wm = w >> 1, wn = w & 1;

    const int srow = w * 32 + (lane >> 2);
    const int kcol = (lane & 3) * 8;
    const _Float16* gBh = Bh + (size_t)(cbk * 128 + srow) * 512 + kcol;
    const _Float16* gBl = Bl + (size_t)(cbk * 128 + srow) * 512 + kcol;

    for (int g = blockIdx.y; g * 128 < count; g += gridDim.y) {
        __syncthreads();
        if (t < 128) {
            int p = g * 128 + t;
            rowidx[t] = (p < count) ? list[p] : list[0];
        }
        __syncthreads();

        f32x4 acc[4][4], acc2[4][4];
        const f32x4 z = {0.f, 0.f, 0.f, 0.f};
        #pragma unroll
        for (int i = 0; i < 4; ++i)
            #pragma unroll
            for (int j = 0; j < 4; ++j) { acc[i][j] = z; acc2[i][j] = z; }

        for (int ks = 0; ks < 16; ++ks) {
            const int ko = ks * 32;
            __syncthreads();
            gl_lds16(gBh + ko, &sBh[w * 1024]);
            gl_lds16(gBh + ko + (size_t)16 * 512, &sBh[w * 1024 + 512]);
            gl_lds16(gBl + ko, &sBl[w * 1024]);
            gl_lds16(gBl + ko + (size_t)16 * 512, &sBl[w * 1024 + 512]);
            #pragma unroll
            for (int i = 0; i < 2; ++i) {
                int idx = i * 256 + t;          // 0..511
                int row = idx >> 2, seg = (idx & 3) * 8;
                size_t src = (size_t)rowidx[row] * 512 + ko + seg;
                *(half8*)&sAh[row * 32 + seg] = *(const half8*)(Ah + src);
                *(half8*)&sAl[row * 32 + seg] = *(const half8*)(Al + src);
            }
            __syncthreads();
            half8 ah[4], al[4], bh[4], bl[4];
            #pragma unroll
            for (int i = 0; i < 4; ++i) {
                ah[i] = *(const half8*)&sAh[(wm * 64 + i * 16 + l15) * 32 + quad * 8];
                al[i] = *(const half8*)&sAl[(wm * 64 + i * 16 + l15) * 32 + quad * 8];
                bh[i] = *(const half8*)&sBh[(wn * 64 + i * 16 + l15) * 32 + quad * 8];
                bl[i] = *(const half8*)&sBl[(wn * 64 + i * 16 + l15) * 32 + quad * 8];
            }
            #pragma unroll
            for (int mi = 0; mi < 4; ++mi)
                #pragma unroll
                for (int ni = 0; ni < 4; ++ni) {
                    acc[mi][ni]  = __builtin_amdgcn_mfma_f32_16x16x32_f16(ah[mi], bh[ni], acc[mi][ni], 0, 0, 0);
                    acc2[mi][ni] = __builtin_amdgcn_mfma_f32_16x16x32_f16(ah[mi], bl[ni], acc2[mi][ni], 0, 0, 0);
                    acc2[mi][ni] = __builtin_amdgcn_mfma_f32_16x16x32_f16(al[mi], bh[ni], acc2[mi][ni], 0, 0, 0);
                }
        }

        #pragma unroll
        for (int mi = 0; mi < 4; ++mi)
            #pragma unroll
            for (int r = 0; r < 4; ++r) {
                float bv = -INFINITY;
                int bi = 0x7fffffff;
                #pragma unroll
                for (int ni = 0; ni < 4; ++ni) {
                    float v = acc[mi][ni][r] + acc2[mi][ni][r] * INV2048;
                    int col = cbk * 128 + wn * 64 + ni * 16 + l15;
                    if (v > bv || (v == bv && col < bi)) { bv = v; bi = col; }
                }
                #pragma unroll
                for (int o = 1; o < 16; o <<= 1) {
                    float ov = __shfl_xor(bv, o, 64);
                    int oi = __shfl_xor(bi, o, 64);
                    if (ov > bv || (ov == bv && oi < bi)) { bv = ov; bi = oi; }
                }
                if (l15 == 0) {
                    int row = wm * 64 + mi * 16 + quad * 4 + r;
                    pvs[row][wn] = bv; pis[row][wn] = bi;
                }
            }
        __syncthreads();
        if (t < 128 && g * 128 + t < count) {
            float v0 = pvs[t][0], v1 = pvs[t][1];
            int i0 = pis[t][0], i1 = pis[t][1];
            bool sw = (v1 > v0) || (v1 == v0 && i1 < i0);
            size_t o = (size_t)(g * 128 + t) * 32 + cbk;
            rpv[o] = sw ? v1 : v0;
            rpi[o] = sw ? i1 : i0;
        }
    }
}

__global__ __launch_bounds__(256) void k_fix(const float* __restrict__ rpv,
                                             const int* __restrict__ rpi,
                                             const int* __restrict__ list,
                                             const int* __restrict__ cnt,
                                             int* __restrict__ out) {
    int p = blockIdx.x * 256 + threadIdx.x;
    if (p >= *cnt) return;
    size_t base = (size_t)p * 32;
    float bv = -INFINITY;
    int bi = 0x7fffffff;
    #pragma unroll
    for (int j = 0; j < 32; ++j) {
        float v = rpv[base + j];
        int ci = rpi[base + j];
        if (v > bv || (v == bv && ci < bi)) { bv = v; bi = ci; }
    }
    out[list[p]] = bi;
}

extern "C" void kernel_launch(void* const* d_in, const int* in_sizes, int n_in,
                              void* d_out, int out_size, void* d_ws, size_t ws_size,
                              hipStream_t stream) {
    const float* x  = (const float*)d_in[0];   // [8,4096,1024]
    const float* rp = (const float*)d_in[1];   // [1024,512]
    const float* cb = (const float*)d_in[2];   // [4096,512]
    int* out = (int*)d_out;                    // [32768] int32

    char* ws = (char*)d_ws;
    _Float16* cn_h   = (_Float16*)(ws);
    _Float16* cn_l   = (_Float16*)(ws + ((size_t)4 << 20));
    _Float16* rpT_h  = (_Float16*)(ws + ((size_t)8 << 20));
    _Float16* rpT_l  = (_Float16*)(ws + ((size_t)9 << 20));
    _Float16* proj_h = (_Float16*)(ws + ((size_t)10 << 20));
    _Float16* proj_l = (_Float16*)(ws + ((size_t)42 << 20));
    float*    pv1    = (float*)   (ws + ((size_t)74 << 20));
    int*      pi1    = (int*)     (ws + ((size_t)78 << 20));
    float*    pv2    = (float*)   (ws + ((size_t)82 << 20));
    float*    rpv    = (float*)   (ws + ((size_t)86 << 20));
    int*      rpi    = (int*)     (ws + ((size_t)90 << 20));
    int*      list   = (int*)     (ws + ((size_t)94 << 20));
    int*      cnt    = (int*)     (ws + ((size_t)94 << 20) + (128 << 10));

    k_prep<<<4224, 256, 0, stream>>>(rp, rpT_h, rpT_l, cb, cn_h, cn_l, cnt);
    k_gemm1<<<dim3(4, 256), 256, 0, stream>>>(x, rpT_h, rpT_l, proj_h, proj_l);
    k_sim_h<<<dim3(32, 256), 256, 0, stream>>>(proj_h, cn_h, pv1, pi1, pv2);
    k_flag<<<128, 256, 0, stream>>>(pv1, pi1, pv2, out, list, cnt);
    k_sim_fix<<<dim3(32, 32), 256, 0, stream>>>(proj_h, proj_l, cn_h, cn_l, list, cnt, rpv, rpi);
    k_fix<<<128, 256, 0, stream>>>(rpv, rpi, list, cnt, out);
}

// Round 9
// 534.057 us; speedup vs baseline: 19.6552x; 1.0502x over previous
//
#include <hip/hip_runtime.h>
#include <math.h>

// B=8, N=4096, D=1024, E=512, C=4096.  M = 32768.
// Split-fp16 MFMA emulation of fp32 GEMM (a = h + l/2048, 3 MFMAs) for proj;
// hi-only fp16 pass for sim + deterministic margin rescue (MARGIN=0.03 >
// worst-case 2^-10*||p||*||c|| + eps); contested rows recomputed exactly.
// R9: k_sim_h = 128x256 tile, BK=64, cbk grid 16. Same 48 KB LDS (staging
//     union epilogue table); 4x output*K per barrier pair, 25% less LDS
//     traffic per output. Swizzle: LDS slot s of row r = global seg s^(r&7).
//
// ws (MB): cn_h 0-4, cn_l 4-8, rpT_h 8-9, rpT_l 9-10, proj_h 10-42,
//          proj_l 42-74, pv1 74-78, pi1 78-82, pv2 82-86, rpv 86-90,
//          rpi 90-94, list 94-94.125, cnt @94.125

typedef _Float16 half8 __attribute__((ext_vector_type(8)));
typedef _Float16 half4 __attribute__((ext_vector_type(4)));
typedef float f32x4 __attribute__((ext_vector_type(4)));
typedef unsigned long long u64;
typedef unsigned int u32;

#define INV2048 (4.8828125e-4f)
#define MARGIN 0.03f

struct Split { _Float16 h, l; };

__device__ __forceinline__ Split split_f32(float v) {
    Split s;
    s.h = (_Float16)v;
    s.l = (_Float16)((v - (float)s.h) * 2048.0f);
    return s;
}

__device__ __forceinline__ void gl_lds16(const void* g, void* l) {
    __builtin_amdgcn_global_load_lds(
        (const __attribute__((address_space(1))) unsigned int*)g,
        (__attribute__((address_space(3))) unsigned int*)l, 16, 0, 0);
}

// monotone float->u32 key (finite inputs): order-preserving, key>0
__device__ __forceinline__ u32 fkey(float v) {
    u32 b = __float_as_uint(v);
    return b ^ ((u32)((int)b >> 31) | 0x80000000u);
}
__device__ __forceinline__ float fkeyinv(u32 u) {
    u32 m2 = (u32)((int)u >> 31);
    return __uint_as_float(u ^ ((~m2) | 0x80000000u));
}

// fused: blocks 0..127 transpose+split rp; blocks 128..4223 normalize+split cb
__global__ __launch_bounds__(256) void k_prep(const float* __restrict__ rp,
                                              _Float16* __restrict__ th,
                                              _Float16* __restrict__ tl,
                                              const float* __restrict__ cb,
                                              _Float16* __restrict__ ch,
                                              _Float16* __restrict__ cl,
                                              int* __restrict__ cnt) {
    const int t = threadIdx.x;
    if (blockIdx.x == 0 && t == 0) *cnt = 0;
    if (blockIdx.x < 128) {
        __shared__ float tile[64][65];
        const int k0 = (blockIdx.x & 15) * 64, n0 = (blockIdx.x >> 4) * 64;
        const int rr = t >> 6, cc = t & 63;
        #pragma unroll
        for (int i = 0; i < 16; ++i) {
            int r = i * 4 + rr;
            tile[r][cc] = rp[(size_t)(k0 + r) * 512 + n0 + cc];
        }
        __syncthreads();
        #pragma unroll
        for (int i = 0; i < 16; ++i) {
            int n = i * 4 + rr;
            Split s = split_f32(tile[cc][n]);
            size_t o = (size_t)(n0 + n) * 1024 + k0 + cc;
            th[o] = s.h;
            tl[o] = s.l;
        }
    } else {
        const int c = blockIdx.x - 128;
        const float* row = cb + (size_t)c * 512;
        float v0 = row[t];
        float v1 = row[t + 256];
        float ss = v0 * v0 + v1 * v1;
        #pragma unroll
        for (int o = 32; o > 0; o >>= 1) ss += __shfl_down(ss, o, 64);
        __shared__ float wsum[4];
        if ((t & 63) == 0) wsum[t >> 6] = ss;
        __syncthreads();
        float s = 1.0f / fmaxf(sqrtf(wsum[0] + wsum[1] + wsum[2] + wsum[3]), 1e-12f);
        Split s0 = split_f32(v0 * s);
        ch[(size_t)c * 512 + t] = s0.h;
        cl[(size_t)c * 512 + t] = s0.l;
        Split s1 = split_f32(v1 * s);
        ch[(size_t)c * 512 + t + 256] = s1.h;
        cl[(size_t)c * 512 + t + 256] = s1.l;
    }
}

// proj = x @ rp : M=32768, N=512, K=1024. split-fp16 3-MFMA (accurate).
__global__ __launch_bounds__(256, 2) void k_gemm1(const float* __restrict__ X,
                                                  const _Float16* __restrict__ Bh,
                                                  const _Float16* __restrict__ Bl,
                                                  _Float16* __restrict__ Ph,
                                                  _Float16* __restrict__ Pl) {
    __shared__ _Float16 sAh[128 * 32], sAl[128 * 32], sBh[128 * 32], sBl[128 * 32];
    const int t = threadIdx.x;
    const int nb = blockIdx.x;   // 0..3
    const int mb = blockIdx.y;   // 0..255
    const int lane = t & 63, w = t >> 6;
    const int quad = lane >> 4, l15 = lane & 15;
    const int wm = w >> 1, wn = w & 1;

    f32x4 acc[4][4], acc2[4][4];
    const f32x4 z = {0.f, 0.f, 0.f, 0.f};
    #pragma unroll
    for (int i = 0; i < 4; ++i)
        #pragma unroll
        for (int j = 0; j < 4; ++j) { acc[i][j] = z; acc2[i][j] = z; }

    const int srow = w * 32 + (lane >> 2);
    const int kcol = (lane & 3) * 8;
    const _Float16* gBh = Bh + (size_t)(nb * 128 + srow) * 1024 + kcol;
    const _Float16* gBl = Bl + (size_t)(nb * 128 + srow) * 1024 + kcol;
    const float* Xb = X + (size_t)(mb * 128) * 1024;

    for (int ks = 0; ks < 32; ++ks) {
        const int ko = ks * 32;
        __syncthreads();
        gl_lds16(gBh + ko, &sBh[w * 1024]);
        gl_lds16(gBh + ko + (size_t)16 * 1024, &sBh[w * 1024 + 512]);
        gl_lds16(gBl + ko, &sBl[w * 1024]);
        gl_lds16(gBl + ko + (size_t)16 * 1024, &sBl[w * 1024 + 512]);
        #pragma unroll
        for (int i = 0; i < 4; ++i) {
            int c = i * 256 + t;
            int row = c >> 3, kq = (c & 7) * 4;
            float4 v = *(const float4*)(Xb + (size_t)row * 1024 + ko + kq);
            Split sx = split_f32(v.x), sy = split_f32(v.y);
            Split sz = split_f32(v.z), sw = split_f32(v.w);
            half4 hv, lv;
            hv.x = sx.h; hv.y = sy.h; hv.z = sz.h; hv.w = sw.h;
            lv.x = sx.l; lv.y = sy.l; lv.z = sz.l; lv.w = sw.l;
            *(half4*)&sAh[row * 32 + kq] = hv;
            *(half4*)&sAl[row * 32 + kq] = lv;
        }
        __syncthreads();
        half8 ah[4], al[4], bh[4], bl[4];
        #pragma unroll
        for (int i = 0; i < 4; ++i) {
            ah[i] = *(const half8*)&sAh[(wm * 64 + i * 16 + l15) * 32 + quad * 8];
            al[i] = *(const half8*)&sAl[(wm * 64 + i * 16 + l15) * 32 + quad * 8];
            bh[i] = *(const half8*)&sBh[(wn * 64 + i * 16 + l15) * 32 + quad * 8];
            bl[i] = *(const half8*)&sBl[(wn * 64 + i * 16 + l15) * 32 + quad * 8];
        }
        #pragma unroll
        for (int mi = 0; mi < 4; ++mi)
            #pragma unroll
            for (int ni = 0; ni < 4; ++ni) {
                acc[mi][ni]  = __builtin_amdgcn_mfma_f32_16x16x32_f16(ah[mi], bh[ni], acc[mi][ni], 0, 0, 0);
                acc2[mi][ni] = __builtin_amdgcn_mfma_f32_16x16x32_f16(ah[mi], bl[ni], acc2[mi][ni], 0, 0, 0);
                acc2[mi][ni] = __builtin_amdgcn_mfma_f32_16x16x32_f16(al[mi], bh[ni], acc2[mi][ni], 0, 0, 0);
            }
    }
    #pragma unroll
    for (int mi = 0; mi < 4; ++mi)
        #pragma unroll
        for (int r = 0; r < 4; ++r) {
            int row = mb * 128 + wm * 64 + mi * 16 + quad * 4 + r;
            #pragma unroll
            for (int ni = 0; ni < 4; ++ni) {
                int col = nb * 128 + wn * 64 + ni * 16 + l15;
                float v = acc[mi][ni][r] + acc2[mi][ni][r] * INV2048;
                Split s = split_f32(v);
                Ph[(size_t)row * 512 + col] = s.h;
                Pl[(size_t)row * 512 + col] = s.l;
            }
        }
}

// PASS 1: hi-only sim. 128m x 256c tile, BK=64, 8 K-iters, 2 barriers/iter.
// Swizzle: LDS slot s (16B units, 8/row) of row r holds global seg s^(r&7).
__global__ __launch_bounds__(256, 2) void k_sim_h(const _Float16* __restrict__ Ah,
                                                  const _Float16* __restrict__ Bh,
                                                  float* __restrict__ pv1,
                                                  int* __restrict__ pi1,
                                                  float* __restrict__ pv2) {
    __shared__ __align__(16) long long smem64[6144];   // 48 KB
    _Float16* sA = (_Float16*)smem64;                  // [128][64] halfs, 16 KB
    _Float16* sB = sA + 128 * 64;                      // [256][64] halfs, 32 KB
    u64* ept = (u64*)smem64;                           // [128][32] u64, 32 KB
    u32* epv = (u32*)((char*)smem64 + 32768);          // [128][32] u32, 16 KB
    const int t = threadIdx.x;
    const int cbk = blockIdx.x;  // 0..15 (256-wide c-tiles)
    const int mb = blockIdx.y;   // 0..255
    const int lane = t & 63, w = t >> 6;
    const int quad = lane >> 4, l15 = lane & 15;
    const int wm = w >> 1, wn = w & 1;

    f32x4 acc[4][8];
    const f32x4 z = {0.f, 0.f, 0.f, 0.f};
    #pragma unroll
    for (int i = 0; i < 4; ++i)
        #pragma unroll
        for (int j = 0; j < 8; ++j) acc[i][j] = z;

    // staging: chunk = 8 rows x 128 B. lane ell -> row ell>>3, global seg
    // (ell&7)^(ell>>3); LDS dest contiguous (base + ell*16B).
    const int srow8 = lane >> 3;                 // 0..7
    const int sseg = (lane & 7) ^ srow8;         // 0..7
    const _Float16* gA = Ah + (size_t)(mb * 128 + w * 32 + srow8) * 512 + sseg * 8;
    const _Float16* gB = Bh + (size_t)(cbk * 256 + w * 64 + srow8) * 512 + sseg * 8;

    for (int ks = 0; ks < 8; ++ks) {
        const int ko = ks * 64;
        __syncthreads();
        #pragma unroll
        for (int c = 0; c < 4; ++c)                  // A: wave stages 32 rows
            gl_lds16(gA + ko + (size_t)(c * 8) * 512, &sA[(w * 32 + c * 8) * 64]);
        #pragma unroll
        for (int c = 0; c < 8; ++c)                  // B: wave stages 64 rows
            gl_lds16(gB + ko + (size_t)(c * 8) * 512, &sB[(w * 64 + c * 8) * 64]);
        __syncthreads();
        #pragma unroll
        for (int phase = 0; phase < 2; ++phase) {
            const int slot = (((phase << 2) | quad) ^ (l15 & 7)) * 8;
            half8 a[4], b[8];
            #pragma unroll
            for (int i = 0; i < 4; ++i)
                a[i] = *(const half8*)&sA[(wm * 64 + i * 16 + l15) * 64 + slot];
            #pragma unroll
            for (int j = 0; j < 8; ++j)
                b[j] = *(const half8*)&sB[(wn * 128 + j * 16 + l15) * 64 + slot];
            #pragma unroll
            for (int mi = 0; mi < 4; ++mi)
                #pragma unroll
                for (int ni = 0; ni < 8; ++ni)
                    acc[mi][ni] = __builtin_amdgcn_mfma_f32_16x16x32_f16(a[mi], b[ni], acc[mi][ni], 0, 0, 0);
        }
    }

    __syncthreads();   // staging dead; reuse LDS as epilogue table
    #pragma unroll
    for (int mi = 0; mi < 4; ++mi)
        #pragma unroll
        for (int r = 0; r < 4; ++r) {
            int row = wm * 64 + mi * 16 + quad * 4 + r;
            u64 p1 = 0, p2 = 0;
            #pragma unroll
            for (int ni = 0; ni < 8; ++ni) {
                float v = acc[mi][ni][r];
                u32 col = cbk * 256 + wn * 128 + ni * 16 + l15;
                u64 p = ((u64)fkey(v) << 32) | (u32)(~col);
                if (p > p1) { p2 = p1; p1 = p; }
                else if (p > p2) p2 = p;
            }
            int e = row * 32 + wn * 16 + l15;
            ept[e] = p1;
            epv[e] = (u32)(p2 >> 32);
        }
    __syncthreads();
    if (t < 128) {
        u64 b1 = 0, b2 = 0;
        u32 vk2 = 0;
        #pragma unroll
        for (int jj = 0; jj < 32; ++jj) {
            int j = (jj + t) & 31;
            u64 p = ept[t * 32 + j];
            if (p > b1) { b2 = b1; b1 = p; }
            else if (p > b2) b2 = p;
            u32 vk = epv[t * 32 + j];
            vk2 = vk > vk2 ? vk : vk2;
        }
        u32 k2 = (u32)(b2 >> 32);
        if (vk2 > k2) k2 = vk2;
        size_t o = (size_t)(mb * 128 + t) * 16 + cbk;
        pv1[o] = fkeyinv((u32)(b1 >> 32));
        pi1[o] = (int)(~(u32)b1);
        pv2[o] = fkeyinv(k2);
    }
}

// reduce 16 c-tile partials; commit confident rows, queue contested ones
__global__ __launch_bounds__(256) void k_flag(const float* __restrict__ pv1,
                                              const int* __restrict__ pi1,
                                              const float* __restrict__ pv2,
                                              int* __restrict__ out,
                                              int* __restrict__ list,
                                              int* __restrict__ cnt) {
    int r = blockIdx.x * 256 + threadIdx.x;
    if (r >= 32768) return;
    size_t base = (size_t)r * 16;
    float v1 = pv1[base], v2 = pv2[base];
    int i1 = pi1[base];
    #pragma unroll
    for (int j = 1; j < 16; ++j) {
        float ov1 = pv1[base + j], ov2 = pv2[base + j];
        int oi1 = pi1[base + j];
        if (ov1 > v1 || (ov1 == v1 && oi1 < i1)) { v2 = fmaxf(v1, ov2); v1 = ov1; i1 = oi1; }
        else v2 = fmaxf(v2, ov1);
    }
    out[r] = i1;
    if (v1 - v2 < MARGIN) {
        int p = atomicAdd(cnt, 1);
        list[p] = r;
    }
}

// PASS 2: exact 3-MFMA sim on gathered contested rows
__global__ __launch_bounds__(256, 2) void k_sim_fix(const _Float16* __restrict__ Ah,
                                                    const _Float16* __restrict__ Al,
                                                    const _Float16* __restrict__ Bh,
                                                    const _Float16* __restrict__ Bl,
                                                    const int* __restrict__ list,
                                                    const int* __restrict__ cnt,
                                                    float* __restrict__ rpv,
                                                    int* __restrict__ rpi) {
    __shared__ _Float16 sAh[128 * 32], sAl[128 * 32], sBh[128 * 32], sBl[128 * 32];
    __shared__ int rowidx[128];
    __shared__ float pvs[128][2];
    __shared__ int   pis[128][2];
    const int count = *cnt;
    const int t = threadIdx.x;
    const int cbk = blockIdx.x;  // 0..31
    const int lane = t & 63, w = t >> 6;
    const int quad = lane >> 4, l15 = lane & 15;
    const int wm = w >> 1, wn = w & 1;

    const int srow = w * 32 + (lane >> 2);
    const int kcol = (lane & 3) * 8;
    const _Float16* gBh = Bh + (size_t)(cbk * 128 + srow) * 512 + kcol;
    const _Float16* gBl = Bl + (size_t)(cbk * 128 + srow) * 512 + kcol;

    for (int g = blockIdx.y; g * 128 < count; g += gridDim.y) {
        __syncthreads();
        if (t < 128) {
            int p = g * 128 + t;
            rowidx[t] = (p < count) ? list[p] : list[0];
        }
        __syncthreads();

        f32x4 acc[4][4], acc2[4][4];
        const f32x4 z = {0.f, 0.f, 0.f, 0.f};
        #pragma unroll
        for (int i = 0; i < 4; ++i)
            #pragma unroll
            for (int j = 0; j < 4; ++j) { acc[i][j] = z; acc2[i][j] = z; }

        for (int ks = 0; ks < 16; ++ks) {
            const int ko = ks * 32;
            __syncthreads();
            gl_lds16(gBh + ko, &sBh[w * 1024]);
            gl_lds16(gBh + ko + (size_t)16 * 512, &sBh[w * 1024 + 512]);
            gl_lds16(gBl + ko, &sBl[w * 1024]);
            gl_lds16(gBl + ko + (size_t)16 * 512, &sBl[w * 1024 + 512]);
            #pragma unroll
            for (int i = 0; i < 2; ++i) {
                int idx = i * 256 + t;          // 0..511
                int row = idx >> 2, seg = (idx & 3) * 8;
                size_t src = (size_t)rowidx[row] * 512 + ko + seg;
                *(half8*)&sAh[row * 32 + seg] = *(const half8*)(Ah + src);
                *(half8*)&sAl[row * 32 + seg] = *(const half8*)(Al + src);
            }
            __syncthreads();
            half8 ah[4], al[4], bh[4], bl[4];
            #pragma unroll
            for (int i = 0; i < 4; ++i) {
                ah[i] = *(const half8*)&sAh[(wm * 64 + i * 16 + l15) * 32 + quad * 8];
                al[i] = *(const half8*)&sAl[(wm * 64 + i * 16 + l15) * 32 + quad * 8];
                bh[i] = *(const half8*)&sBh[(wn * 64 + i * 16 + l15) * 32 + quad * 8];
                bl[i] = *(const half8*)&sBl[(wn * 64 + i * 16 + l15) * 32 + quad * 8];
            }
            #pragma unroll
            for (int mi = 0; mi < 4; ++mi)
                #pragma unroll
                for (int ni = 0; ni < 4; ++ni) {
                    acc[mi][ni]  = __builtin_amdgcn_mfma_f32_16x16x32_f16(ah[mi], bh[ni], acc[mi][ni], 0, 0, 0);
                    acc2[mi][ni] = __builtin_amdgcn_mfma_f32_16x16x32_f16(ah[mi], bl[ni], acc2[mi][ni], 0, 0, 0);
                    acc2[mi][ni] = __builtin_amdgcn_mfma_f32_16x16x32_f16(al[mi], bh[ni], acc2[mi][ni], 0, 0, 0);
                }
        }

        #pragma unroll
        for (int mi = 0; mi < 4; ++mi)
            #pragma unroll
            for (int r = 0; r < 4; ++r) {
                float bv = -INFINITY;
                int bi = 0x7fffffff;
                #pragma unroll
                for (int ni = 0; ni < 4; ++ni) {
                    float v = acc[mi][ni][r] + acc2[mi][ni][r] * INV2048;
                    int col = cbk * 128 + wn * 64 + ni * 16 + l15;
                    if (v > bv || (v == bv && col < bi)) { bv = v; bi = col; }
                }
                #pragma unroll
                for (int o = 1; o < 16; o <<= 1) {
                    float ov = __shfl_xor(bv, o, 64);
                    int oi = __shfl_xor(bi, o, 64);
                    if (ov > bv || (ov == bv && oi < bi)) { bv = ov; bi = oi; }
                }
                if (l15 == 0) {
                    int row = wm * 64 + mi * 16 + quad * 4 + r;
                    pvs[row][wn] = bv; pis[row][wn] = bi;
                }
            }
        __syncthreads();
        if (t < 128 && g * 128 + t < count) {
            float v0 = pvs[t][0], v1 = pvs[t][1];
            int i0 = pis[t][0], i1 = pis[t][1];
            bool sw = (v1 > v0) || (v1 == v0 && i1 < i0);
            size_t o = (size_t)(g * 128 + t) * 32 + cbk;
            rpv[o] = sw ? v1 : v0;
            rpi[o] = sw ? i1 : i0;
        }
    }
}

__global__ __launch_bounds__(256) void k_fix(const float* __restrict__ rpv,
                                             const int* __restrict__ rpi,
                                             const int* __restrict__ list,
                                             const int* __restrict__ cnt,
                                             int* __restrict__ out) {
    int p = blockIdx.x * 256 + threadIdx.x;
    if (p >= *cnt) return;
    size_t base = (size_t)p * 32;
    float bv = -INFINITY;
    int bi = 0x7fffffff;
    #pragma unroll
    for (int j = 0; j < 32; ++j) {
        float v = rpv[base + j];
        int ci = rpi[base + j];
        if (v > bv || (v == bv && ci < bi)) { bv = v; bi = ci; }
    }
    out[list[p]] = bi;
}

extern "C" void kernel_launch(void* const* d_in, const int* in_sizes, int n_in,
                              void* d_out, int out_size, void* d_ws, size_t ws_size,
                              hipStream_t stream) {
    const float* x  = (const float*)d_in[0];   // [8,4096,1024]
    const float* rp = (const float*)d_in[1];   // [1024,512]
    const float* cb = (const float*)d_in[2];   // [4096,512]
    int* out = (int*)d_out;                    // [32768] int32

    char* ws = (char*)d_ws;
    _Float16* cn_h   = (_Float16*)(ws);
    _Float16* cn_l   = (_Float16*)(ws + ((size_t)4 << 20));
    _Float16* rpT_h  = (_Float16*)(ws + ((size_t)8 << 20));
    _Float16* rpT_l  = (_Float16*)(ws + ((size_t)9 << 20));
    _Float16* proj_h = (_Float16*)(ws + ((size_t)10 << 20));
    _Float16* proj_l = (_Float16*)(ws + ((size_t)42 << 20));
    float*    pv1    = (float*)   (ws + ((size_t)74 << 20));
    int*      pi1    = (int*)     (ws + ((size_t)78 << 20));
    float*    pv2    = (float*)   (ws + ((size_t)82 << 20));
    float*    rpv    = (float*)   (ws + ((size_t)86 << 20));
    int*      rpi    = (int*)     (ws + ((size_t)90 << 20));
    int*      list   = (int*)     (ws + ((size_t)94 << 20));
    int*      cnt    = (int*)     (ws + ((size_t)94 << 20) + (128 << 10));

    k_prep<<<4224, 256, 0, stream>>>(rp, rpT_h, rpT_l, cb, cn_h, cn_l, cnt);
    k_gemm1<<<dim3(4, 256), 256, 0, stream>>>(x, rpT_h, rpT_l, proj_h, proj_l);
    k_sim_h<<<dim3(16, 256), 256, 0, stream>>>(proj_h, cn_h, pv1, pi1, pv2);
    k_flag<<<128, 256, 0, stream>>>(pv1, pi1, pv2, out, list, cnt);
    k_sim_fix<<<dim3(32, 32), 256, 0, stream>>>(proj_h, proj_l, cn_h, cn_l, list, cnt, rpv, rpi);
    k_fix<<<128, 256, 0, stream>>>(rpv, rpi, list, cnt, out);
}

// Round 10
// 533.474 us; speedup vs baseline: 19.6767x; 1.0011x over previous
//
#include <hip/hip_runtime.h>
#include <math.h>

// B=8, N=4096, D=1024, E=512, C=4096.  M = 32768.
// Split-fp16 MFMA emulation of fp32 GEMM (a = h + l/2048, 3 MFMAs) for proj;
// hi-only fp16 pass for sim + deterministic margin rescue (MARGIN=0.03 >
// worst-case 2^-10*||p||*||c|| + eps); contested rows recomputed exactly.
// R10: k_gemm1 ported to the r9 structure — BK=64 (16 iters, half the
//      barriers), XOR 16B-slot swizzle (slot s of row r at s^(r&7); reads at
//      (phase*4+quad)^(l15&7) -> 2 lanes/bank, conflict-free), X staged as
//      half8 writes, B via 8rowx128B gl_lds chunks. MFMA order bit-identical.
//
// ws (MB): cn_h 0-4, cn_l 4-8, rpT_h 8-9, rpT_l 9-10, proj_h 10-42,
//          proj_l 42-74, pv1 74-78, pi1 78-82, pv2 82-86, rpv 86-90,
//          rpi 90-94, list 94-94.125, cnt @94.125

typedef _Float16 half8 __attribute__((ext_vector_type(8)));
typedef _Float16 half4 __attribute__((ext_vector_type(4)));
typedef float f32x4 __attribute__((ext_vector_type(4)));
typedef unsigned long long u64;
typedef unsigned int u32;

#define INV2048 (4.8828125e-4f)
#define MARGIN 0.03f

struct Split { _Float16 h, l; };

__device__ __forceinline__ Split split_f32(float v) {
    Split s;
    s.h = (_Float16)v;
    s.l = (_Float16)((v - (float)s.h) * 2048.0f);
    return s;
}

__device__ __forceinline__ void gl_lds16(const void* g, void* l) {
    __builtin_amdgcn_global_load_lds(
        (const __attribute__((address_space(1))) unsigned int*)g,
        (__attribute__((address_space(3))) unsigned int*)l, 16, 0, 0);
}

// monotone float->u32 key (finite inputs): order-preserving, key>0
__device__ __forceinline__ u32 fkey(float v) {
    u32 b = __float_as_uint(v);
    return b ^ ((u32)((int)b >> 31) | 0x80000000u);
}
__device__ __forceinline__ float fkeyinv(u32 u) {
    u32 m2 = (u32)((int)u >> 31);
    return __uint_as_float(u ^ ((~m2) | 0x80000000u));
}

// fused: blocks 0..127 transpose+split rp; blocks 128..4223 normalize+split cb
__global__ __launch_bounds__(256) void k_prep(const float* __restrict__ rp,
                                              _Float16* __restrict__ th,
                                              _Float16* __restrict__ tl,
                                              const float* __restrict__ cb,
                                              _Float16* __restrict__ ch,
                                              _Float16* __restrict__ cl,
                                              int* __restrict__ cnt) {
    const int t = threadIdx.x;
    if (blockIdx.x == 0 && t == 0) *cnt = 0;
    if (blockIdx.x < 128) {
        __shared__ float tile[64][65];
        const int k0 = (blockIdx.x & 15) * 64, n0 = (blockIdx.x >> 4) * 64;
        const int rr = t >> 6, cc = t & 63;
        #pragma unroll
        for (int i = 0; i < 16; ++i) {
            int r = i * 4 + rr;
            tile[r][cc] = rp[(size_t)(k0 + r) * 512 + n0 + cc];
        }
        __syncthreads();
        #pragma unroll
        for (int i = 0; i < 16; ++i) {
            int n = i * 4 + rr;
            Split s = split_f32(tile[cc][n]);
            size_t o = (size_t)(n0 + n) * 1024 + k0 + cc;
            th[o] = s.h;
            tl[o] = s.l;
        }
    } else {
        const int c = blockIdx.x - 128;
        const float* row = cb + (size_t)c * 512;
        float v0 = row[t];
        float v1 = row[t + 256];
        float ss = v0 * v0 + v1 * v1;
        #pragma unroll
        for (int o = 32; o > 0; o >>= 1) ss += __shfl_down(ss, o, 64);
        __shared__ float wsum[4];
        if ((t & 63) == 0) wsum[t >> 6] = ss;
        __syncthreads();
        float s = 1.0f / fmaxf(sqrtf(wsum[0] + wsum[1] + wsum[2] + wsum[3]), 1e-12f);
        Split s0 = split_f32(v0 * s);
        ch[(size_t)c * 512 + t] = s0.h;
        cl[(size_t)c * 512 + t] = s0.l;
        Split s1 = split_f32(v1 * s);
        ch[(size_t)c * 512 + t + 256] = s1.h;
        cl[(size_t)c * 512 + t + 256] = s1.l;
    }
}

// proj = x @ rp : M=32768, N=512, K=1024. split-fp16 3-MFMA (accurate).
// R10: BK=64, XOR-swizzled LDS (16B slot s of row r at s^(r&7)).
__global__ __launch_bounds__(256, 2) void k_gemm1(const float* __restrict__ X,
                                                  const _Float16* __restrict__ Bh,
                                                  const _Float16* __restrict__ Bl,
                                                  _Float16* __restrict__ Ph,
                                                  _Float16* __restrict__ Pl) {
    __shared__ _Float16 sAh[128 * 64], sAl[128 * 64];   // 16 KB each
    __shared__ _Float16 sBh[128 * 64], sBl[128 * 64];   // 16 KB each
    const int t = threadIdx.x;
    const int nb = blockIdx.x;   // 0..3
    const int mb = blockIdx.y;   // 0..255
    const int lane = t & 63, w = t >> 6;
    const int quad = lane >> 4, l15 = lane & 15;
    const int wm = w >> 1, wn = w & 1;

    f32x4 acc[4][4], acc2[4][4];
    const f32x4 z = {0.f, 0.f, 0.f, 0.f};
    #pragma unroll
    for (int i = 0; i < 4; ++i)
        #pragma unroll
        for (int j = 0; j < 4; ++j) { acc[i][j] = z; acc2[i][j] = z; }

    // B staging (gl_lds): chunk = 8 rows x 128B; lane ell -> row ell>>3,
    // global seg (ell&7)^(ell>>3). Wave stages 32 rows (4 chunks) of h and l.
    const int srow8 = lane >> 3;
    const int sseg = (lane & 7) ^ srow8;
    const _Float16* gBh = Bh + (size_t)(nb * 128 + w * 32 + srow8) * 1024 + sseg * 8;
    const _Float16* gBl = Bl + (size_t)(nb * 128 + w * 32 + srow8) * 1024 + sseg * 8;

    // X staging (VALU): thread t -> row t>>1, k8 slots (t&1)*4 + j (j=0..3);
    // each slot = 8 fp32 (2 float4) -> half8 h + half8 l at slot^(row&7).
    const int xrow = t >> 1;
    const int xk8 = (t & 1) * 4;
    const float* gX = X + (size_t)(mb * 128 + xrow) * 1024 + xk8 * 8;
    _Float16* wAh = &sAh[xrow * 64];
    _Float16* wAl = &sAl[xrow * 64];
    const int xswz = xrow & 7;

    for (int ks = 0; ks < 16; ++ks) {
        const int ko = ks * 64;
        __syncthreads();
        #pragma unroll
        for (int c = 0; c < 4; ++c) {
            gl_lds16(gBh + ko + (size_t)(c * 8) * 1024, &sBh[(w * 32 + c * 8) * 64]);
            gl_lds16(gBl + ko + (size_t)(c * 8) * 1024, &sBl[(w * 32 + c * 8) * 64]);
        }
        #pragma unroll
        for (int j = 0; j < 4; ++j) {
            float4 v0 = *(const float4*)(gX + ko + j * 8);
            float4 v1 = *(const float4*)(gX + ko + j * 8 + 4);
            Split s0 = split_f32(v0.x), s1 = split_f32(v0.y);
            Split s2 = split_f32(v0.z), s3 = split_f32(v0.w);
            Split s4 = split_f32(v1.x), s5 = split_f32(v1.y);
            Split s6 = split_f32(v1.z), s7 = split_f32(v1.w);
            half8 hv, lv;
            hv[0] = s0.h; hv[1] = s1.h; hv[2] = s2.h; hv[3] = s3.h;
            hv[4] = s4.h; hv[5] = s5.h; hv[6] = s6.h; hv[7] = s7.h;
            lv[0] = s0.l; lv[1] = s1.l; lv[2] = s2.l; lv[3] = s3.l;
            lv[4] = s4.l; lv[5] = s5.l; lv[6] = s6.l; lv[7] = s7.l;
            const int slot = ((xk8 + j) ^ xswz) * 8;
            *(half8*)&wAh[slot] = hv;
            *(half8*)&wAl[slot] = lv;
        }
        __syncthreads();
        #pragma unroll
        for (int phase = 0; phase < 2; ++phase) {
            const int slot = (((phase << 2) | quad) ^ (l15 & 7)) * 8;
            half8 ah[4], al[4], bh[4], bl[4];
            #pragma unroll
            for (int i = 0; i < 4; ++i) {
                ah[i] = *(const half8*)&sAh[(wm * 64 + i * 16 + l15) * 64 + slot];
                al[i] = *(const half8*)&sAl[(wm * 64 + i * 16 + l15) * 64 + slot];
                bh[i] = *(const half8*)&sBh[(wn * 64 + i * 16 + l15) * 64 + slot];
                bl[i] = *(const half8*)&sBl[(wn * 64 + i * 16 + l15) * 64 + slot];
            }
            #pragma unroll
            for (int mi = 0; mi < 4; ++mi)
                #pragma unroll
                for (int ni = 0; ni < 4; ++ni) {
                    acc[mi][ni]  = __builtin_amdgcn_mfma_f32_16x16x32_f16(ah[mi], bh[ni], acc[mi][ni], 0, 0, 0);
                    acc2[mi][ni] = __builtin_amdgcn_mfma_f32_16x16x32_f16(ah[mi], bl[ni], acc2[mi][ni], 0, 0, 0);
                    acc2[mi][ni] = __builtin_amdgcn_mfma_f32_16x16x32_f16(al[mi], bh[ni], acc2[mi][ni], 0, 0, 0);
                }
        }
    }
    #pragma unroll
    for (int mi = 0; mi < 4; ++mi)
        #pragma unroll
        for (int r = 0; r < 4; ++r) {
            int row = mb * 128 + wm * 64 + mi * 16 + quad * 4 + r;
            #pragma unroll
            for (int ni = 0; ni < 4; ++ni) {
                int col = nb * 128 + wn * 64 + ni * 16 + l15;
                float v = acc[mi][ni][r] + acc2[mi][ni][r] * INV2048;
                Split s = split_f32(v);
                Ph[(size_t)row * 512 + col] = s.h;
                Pl[(size_t)row * 512 + col] = s.l;
            }
        }
}

// PASS 1: hi-only sim. 128m x 256c tile, BK=64, 8 K-iters, 2 barriers/iter.
// Swizzle: LDS slot s (16B units, 8/row) of row r holds global seg s^(r&7).
__global__ __launch_bounds__(256, 2) void k_sim_h(const _Float16* __restrict__ Ah,
                                                  const _Float16* __restrict__ Bh,
                                                  float* __restrict__ pv1,
                                                  int* __restrict__ pi1,
                                                  float* __restrict__ pv2) {
    __shared__ __align__(16) long long smem64[6144];   // 48 KB
    _Float16* sA = (_Float16*)smem64;                  // [128][64] halfs, 16 KB
    _Float16* sB = sA + 128 * 64;                      // [256][64] halfs, 32 KB
    u64* ept = (u64*)smem64;                           // [128][32] u64, 32 KB
    u32* epv = (u32*)((char*)smem64 + 32768);          // [128][32] u32, 16 KB
    const int t = threadIdx.x;
    const int cbk = blockIdx.x;  // 0..15 (256-wide c-tiles)
    const int mb = blockIdx.y;   // 0..255
    const int lane = t & 63, w = t >> 6;
    const int quad = lane >> 4, l15 = lane & 15;
    const int wm = w >> 1, wn = w & 1;

    f32x4 acc[4][8];
    const f32x4 z = {0.f, 0.f, 0.f, 0.f};
    #pragma unroll
    for (int i = 0; i < 4; ++i)
        #pragma unroll
        for (int j = 0; j < 8; ++j) acc[i][j] = z;

    const int srow8 = lane >> 3;
    const int sseg = (lane & 7) ^ srow8;
    const _Float16* gA = Ah + (size_t)(mb * 128 + w * 32 + srow8) * 512 + sseg * 8;
    const _Float16* gB = Bh + (size_t)(cbk * 256 + w * 64 + srow8) * 512 + sseg * 8;

    for (int ks = 0; ks < 8; ++ks) {
        const int ko = ks * 64;
        __syncthreads();
        #pragma unroll
        for (int c = 0; c < 4; ++c)
            gl_lds16(gA + ko + (size_t)(c * 8) * 512, &sA[(w * 32 + c * 8) * 64]);
        #pragma unroll
        for (int c = 0; c < 8; ++c)
            gl_lds16(gB + ko + (size_t)(c * 8) * 512, &sB[(w * 64 + c * 8) * 64]);
        __syncthreads();
        #pragma unroll
        for (int phase = 0; phase < 2; ++phase) {
            const int slot = (((phase << 2) | quad) ^ (l15 & 7)) * 8;
            half8 a[4], b[8];
            #pragma unroll
            for (int i = 0; i < 4; ++i)
                a[i] = *(const half8*)&sA[(wm * 64 + i * 16 + l15) * 64 + slot];
            #pragma unroll
            for (int j = 0; j < 8; ++j)
                b[j] = *(const half8*)&sB[(wn * 128 + j * 16 + l15) * 64 + slot];
            #pragma unroll
            for (int mi = 0; mi < 4; ++mi)
                #pragma unroll
                for (int ni = 0; ni < 8; ++ni)
                    acc[mi][ni] = __builtin_amdgcn_mfma_f32_16x16x32_f16(a[mi], b[ni], acc[mi][ni], 0, 0, 0);
        }
    }

    __syncthreads();   // staging dead; reuse LDS as epilogue table
    #pragma unroll
    for (int mi = 0; mi < 4; ++mi)
        #pragma unroll
        for (int r = 0; r < 4; ++r) {
            int row = wm * 64 + mi * 16 + quad * 4 + r;
            u64 p1 = 0, p2 = 0;
            #pragma unroll
            for (int ni = 0; ni < 8; ++ni) {
                float v = acc[mi][ni][r];
                u32 col = cbk * 256 + wn * 128 + ni * 16 + l15;
                u64 p = ((u64)fkey(v) << 32) | (u32)(~col);
                if (p > p1) { p2 = p1; p1 = p; }
                else if (p > p2) p2 = p;
            }
            int e = row * 32 + wn * 16 + l15;
            ept[e] = p1;
            epv[e] = (u32)(p2 >> 32);
        }
    __syncthreads();
    if (t < 128) {
        u64 b1 = 0, b2 = 0;
        u32 vk2 = 0;
        #pragma unroll
        for (int jj = 0; jj < 32; ++jj) {
            int j = (jj + t) & 31;
            u64 p = ept[t * 32 + j];
            if (p > b1) { b2 = b1; b1 = p; }
            else if (p > b2) b2 = p;
            u32 vk = epv[t * 32 + j];
            vk2 = vk > vk2 ? vk : vk2;
        }
        u32 k2 = (u32)(b2 >> 32);
        if (vk2 > k2) k2 = vk2;
        size_t o = (size_t)(mb * 128 + t) * 16 + cbk;
        pv1[o] = fkeyinv((u32)(b1 >> 32));
        pi1[o] = (int)(~(u32)b1);
        pv2[o] = fkeyinv(k2);
    }
}

// reduce 16 c-tile partials; commit confident rows, queue contested ones
__global__ __launch_bounds__(256) void k_flag(const float* __restrict__ pv1,
                                              const int* __restrict__ pi1,
                                              const float* __restrict__ pv2,
                                              int* __restrict__ out,
                                              int* __restrict__ list,
                                              int* __restrict__ cnt) {
    int r = blockIdx.x * 256 + threadIdx.x;
    if (r >= 32768) return;
    size_t base = (size_t)r * 16;
    float v1 = pv1[base], v2 = pv2[base];
    int i1 = pi1[base];
    #pragma unroll
    for (int j = 1; j < 16; ++j) {
        float ov1 = pv1[base + j], ov2 = pv2[base + j];
        int oi1 = pi1[base + j];
        if (ov1 > v1 || (ov1 == v1 && oi1 < i1)) { v2 = fmaxf(v1, ov2); v1 = ov1; i1 = oi1; }
        else v2 = fmaxf(v2, ov1);
    }
    out[r] = i1;
    if (v1 - v2 < MARGIN) {
        int p = atomicAdd(cnt, 1);
        list[p] = r;
    }
}

// PASS 2: exact 3-MFMA sim on gathered contested rows
__global__ __launch_bounds__(256, 2) void k_sim_fix(const _Float16* __restrict__ Ah,
                                                    const _Float16* __restrict__ Al,
                                                    const _Float16* __restrict__ Bh,
                                                    const _Float16* __restrict__ Bl,
                                                    const int* __restrict__ list,
                                                    const int* __restrict__ cnt,
                                                    float* __restrict__ rpv,
                                                    int* __restrict__ rpi) {
    __shared__ _Float16 sAh[128 * 32], sAl[128 * 32], sBh[128 * 32], sBl[128 * 32];
    __shared__ int rowidx[128];
    __shared__ float pvs[128][2];
    __shared__ int   pis[128][2];
    const int count = *cnt;
    const int t = threadIdx.x;
    const int cbk = blockIdx.x;  // 0..31
    const int lane = t & 63, w = t >> 6;
    const int quad = lane >> 4, l15 = lane & 15;
    const int wm = w >> 1, wn = w & 1;

    const int srow = w * 32 + (lane >> 2);
    const int kcol = (lane & 3) * 8;
    const _Float16* gBh = Bh + (size_t)(cbk * 128 + srow) * 512 + kcol;
    const _Float16* gBl = Bl + (size_t)(cbk * 128 + srow) * 512 + kcol;

    for (int g = blockIdx.y; g * 128 < count; g += gridDim.y) {
        __syncthreads();
        if (t < 128) {
            int p = g * 128 + t;
            rowidx[t] = (p < count) ? list[p] : list[0];
        }
        __syncthreads();

        f32x4 acc[4][4], acc2[4][4];
        const f32x4 z = {0.f, 0.f, 0.f, 0.f};
        #pragma unroll
        for (int i = 0; i < 4; ++i)
            #pragma unroll
            for (int j = 0; j < 4; ++j) { acc[i][j] = z; acc2[i][j] = z; }

        for (int ks = 0; ks < 16; ++ks) {
            const int ko = ks * 32;
            __syncthreads();
            gl_lds16(gBh + ko, &sBh[w * 1024]);
            gl_lds16(gBh + ko + (size_t)16 * 512, &sBh[w * 1024 + 512]);
            gl_lds16(gBl + ko, &sBl[w * 1024]);
            gl_lds16(gBl + ko + (size_t)16 * 512, &sBl[w * 1024 + 512]);
            #pragma unroll
            for (int i = 0; i < 2; ++i) {
                int idx = i * 256 + t;          // 0..511
                int row = idx >> 2, seg = (idx & 3) * 8;
                size_t src = (size_t)rowidx[row] * 512 + ko + seg;
                *(half8*)&sAh[row * 32 + seg] = *(const half8*)(Ah + src);
                *(half8*)&sAl[row * 32 + seg] = *(const half8*)(Al + src);
            }
            __syncthreads();
            half8 ah[4], al[4], bh[4], bl[4];
            #pragma unroll
            for (int i = 0; i < 4; ++i) {
                ah[i] = *(const half8*)&sAh[(wm * 64 + i * 16 + l15) * 32 + quad * 8];
                al[i] = *(const half8*)&sAl[(wm * 64 + i * 16 + l15) * 32 + quad * 8];
                bh[i] = *(const half8*)&sBh[(wn * 64 + i * 16 + l15) * 32 + quad * 8];
                bl[i] = *(const half8*)&sBl[(wn * 64 + i * 16 + l15) * 32 + quad * 8];
            }
            #pragma unroll
            for (int mi = 0; mi < 4; ++mi)
                #pragma unroll
                for (int ni = 0; ni < 4; ++ni) {
                    acc[mi][ni]  = __builtin_amdgcn_mfma_f32_16x16x32_f16(ah[mi], bh[ni], acc[mi][ni], 0, 0, 0);
                    acc2[mi][ni] = __builtin_amdgcn_mfma_f32_16x16x32_f16(ah[mi], bl[ni], acc2[mi][ni], 0, 0, 0);
                    acc2[mi][ni] = __builtin_amdgcn_mfma_f32_16x16x32_f16(al[mi], bh[ni], acc2[mi][ni], 0, 0, 0);
                }
        }

        #pragma unroll
        for (int mi = 0; mi < 4; ++mi)
            #pragma unroll
            for (int r = 0; r < 4; ++r) {
                float bv = -INFINITY;
                int bi = 0x7fffffff;
                #pragma unroll
                for (int ni = 0; ni < 4; ++ni) {
                    float v = acc[mi][ni][r] + acc2[mi][ni][r] * INV2048;
                    int col = cbk * 128 + wn * 64 + ni * 16 + l15;
                    if (v > bv || (v == bv && col < bi)) { bv = v; bi = col; }
                }
                #pragma unroll
                for (int o = 1; o < 16; o <<= 1) {
                    float ov = __shfl_xor(bv, o, 64);
                    int oi = __shfl_xor(bi, o, 64);
                    if (ov > bv || (ov == bv && oi < bi)) { bv = ov; bi = oi; }
                }
                if (l15 == 0) {
                    int row = wm * 64 + mi * 16 + quad * 4 + r;
                    pvs[row][wn] = bv; pis[row][wn] = bi;
                }
            }
        __syncthreads();
        if (t < 128 && g * 128 + t < count) {
            float v0 = pvs[t][0], v1 = pvs[t][1];
            int i0 = pis[t][0], i1 = pis[t][1];
            bool sw = (v1 > v0) || (v1 == v0 && i1 < i0);
            size_t o = (size_t)(g * 128 + t) * 32 + cbk;
            rpv[o] = sw ? v1 : v0;
            rpi[o] = sw ? i1 : i0;
        }
    }
}

__global__ __launch_bounds__(256) void k_fix(const float* __restrict__ rpv,
                                             const int* __restrict__ rpi,
                                             const int* __restrict__ list,
                                             const int* __restrict__ cnt,
                                             int* __restrict__ out) {
    int p = blockIdx.x * 256 + threadIdx.x;
    if (p >= *cnt) return;
    size_t base = (size_t)p * 32;
    float bv = -INFINITY;
    int bi = 0x7fffffff;
    #pragma unroll
    for (int j = 0; j < 32; ++j) {
        float v = rpv[base + j];
        int ci = rpi[base + j];
        if (v > bv || (v == bv && ci < bi)) { bv = v; bi = ci; }
    }
    out[list[p]] = bi;
}

extern "C" void kernel_launch(void* const* d_in, const int* in_sizes, int n_in,
                              void* d_out, int out_size, void* d_ws, size_t ws_size,
                              hipStream_t stream) {
    const float* x  = (const float*)d_in[0];   // [8,4096,1024]
    const float* rp = (const float*)d_in[1];   // [1024,512]
    const float* cb = (const float*)d_in[2];   // [4096,512]
    int* out = (int*)d_out;                    // [32768] int32

    char* ws = (char*)d_ws;
    _Float16* cn_h   = (_Float16*)(ws);
    _Float16* cn_l   = (_Float16*)(ws + ((size_t)4 << 20));
    _Float16* rpT_h  = (_Float16*)(ws + ((size_t)8 << 20));
    _Float16* rpT_l  = (_Float16*)(ws + ((size_t)9 << 20));
    _Float16* proj_h = (_Float16*)(ws + ((size_t)10 << 20));
    _Float16* proj_l = (_Float16*)(ws + ((size_t)42 << 20));
    float*    pv1    = (float*)   (ws + ((size_t)74 << 20));
    int*      pi1    = (int*)     (ws + ((size_t)78 << 20));
    float*    pv2    = (float*)   (ws + ((size_t)82 << 20));
    float*    rpv    = (float*)   (ws + ((size_t)86 << 20));
    int*      rpi    = (int*)     (ws + ((size_t)90 << 20));
    int*      list   = (int*)     (ws + ((size_t)94 << 20));
    int*      cnt    = (int*)     (ws + ((size_t)94 << 20) + (128 << 10));

    k_prep<<<4224, 256, 0, stream>>>(rp, rpT_h, rpT_l, cb, cn_h, cn_l, cnt);
    k_gemm1<<<dim3(4, 256), 256, 0, stream>>>(x, rpT_h, rpT_l, proj_h, proj_l);
    k_sim_h<<<dim3(16, 256), 256, 0, stream>>>(proj_h, cn_h, pv1, pi1, pv2);
    k_flag<<<128, 256, 0, stream>>>(pv1, pi1, pv2, out, list, cnt);
    k_sim_fix<<<dim3(32, 32), 256, 0, stream>>>(proj_h, proj_l, cn_h, cn_l, list, cnt, rpv, rpi);
    k_fix<<<128, 256, 0, stream>>>(rpv, rpi, list, cnt, out);
}